// Round 5
// baseline (413.250 us; speedup 1.0000x reference)
//
#include <hip/hip_runtime.h>
#include <hip/hip_bf16.h>

#define B_ 32
#define T_ 40
#define P_ 256
#define V_ 4096
#define D_ 256
#define DINO_ 384
#define H_ 4
#define L_ 2
#define HD_ 64
#define DFF_ 1024
#define EPS_ 1e-5f

typedef __bf16 bf16;
typedef __bf16 bf16x8 __attribute__((ext_vector_type(8)));
typedef float f32x4 __attribute__((ext_vector_type(4)));

__device__ __forceinline__ bf16x8 cvt8(const float* p) {
  float4 f0 = *(const float4*)p;
  float4 f1 = *(const float4*)(p + 4);
  bf16x8 v;
  v[0] = (bf16)f0.x; v[1] = (bf16)f0.y; v[2] = (bf16)f0.z; v[3] = (bf16)f0.w;
  v[4] = (bf16)f1.x; v[5] = (bf16)f1.y; v[6] = (bf16)f1.z; v[7] = (bf16)f1.w;
  return v;
}

// ---------------- prep: embedding (blocks 0..1279) + fus_w2 transpose ------
__global__ __launch_bounds__(256) void prep_k(const int* __restrict__ tokens,
                                              const float* __restrict__ tok_emb,
                                              const float* __restrict__ pos_emb,
                                              float* __restrict__ x,
                                              const float* __restrict__ fus_w2,
                                              float* __restrict__ w2T) {
  __shared__ float tile[32][33];
  int bi = blockIdx.x;
  if (bi < B_ * T_) {
    int t = bi % T_;
    int d = threadIdx.x;
    x[bi * D_ + d] = tok_emb[tokens[bi] * D_ + d] + pos_emb[t * D_ + d];
  } else {
    int tt = bi - B_ * T_;  // 0..63
    int bx = (tt & 7) * 32, by = (tt >> 3) * 32;
    int tx = threadIdx.x & 31, ty = threadIdx.x >> 5;  // 32 x 8
#pragma unroll
    for (int i = 0; i < 32; i += 8) tile[ty + i][tx] = fus_w2[(by + ty + i) * D_ + bx + tx];
    __syncthreads();
#pragma unroll
    for (int i = 0; i < 32; i += 8) w2T[(bx + ty + i) * D_ + by + tx] = tile[tx][ty + i];
  }
}

// ---------------- direct MFMA GEMM (no LDS): 32x32 tile/block, 4 waves -----
// C[m,n] = act(sum_k A[m,k] * W[n,k] + bias[n]); A,W fp32 row-major.
// Fragments loaded straight from global (everything is L2-resident).
// shiftT: A row m -> (t==0 ? zeros : row m-1), t = m % T_.
// gatherIdx: A row m -> gatherIdx[m]'th row of A.
// Grid: (N/32, M/32, batch). K multiple of 32.
__global__ __launch_bounds__(256) void gemmd_k(
    const float* __restrict__ A, const float* __restrict__ W, const float* __restrict__ bias,
    float* __restrict__ out, int K, int lda, int ldw, int Cm, int Cn,
    long batchA, long batchC, int relu, int shiftT, const int* __restrict__ gatherIdx) {
  const int lane = threadIdx.x & 63;
  const int wv = threadIdx.x >> 6;
  const int mi = wv & 1, ni = wv >> 1;
  const int col = lane & 15;   // fragment row (m for A, n for B)
  const int quad = lane >> 4;  // k-subchunk
  const int bn = blockIdx.x * 32;
  const int bm = blockIdx.y * 32;
  const int rm = bm + mi * 16 + col;
  const float* Af = A + blockIdx.z * batchA;
  float* Cp = out + blockIdx.z * batchC;

  bool zeroA = false;
  long arow;
  if (gatherIdx) {
    arow = (long)gatherIdx[rm] * lda;
  } else if (shiftT) {
    int t = rm % T_;
    zeroA = (t == 0);
    arow = (long)(zeroA ? rm : rm - 1) * lda;
  } else {
    arow = (long)rm * lda;
  }
  const float* Ap = Af + arow + quad * 8;
  const float* Wp = W + (long)(bn + ni * 16 + col) * ldw + quad * 8;

  f32x4 acc = {0.f, 0.f, 0.f, 0.f};
  bf16x8 z8 = {};
#pragma unroll 4
  for (int kk = 0; kk < K; kk += 32) {
    bf16x8 af = cvt8(Ap + kk);
    bf16x8 bf = cvt8(Wp + kk);
    if (zeroA) af = z8;
    acc = __builtin_amdgcn_mfma_f32_16x16x32_bf16(af, bf, acc, 0, 0, 0);
  }

  const int n = bn + ni * 16 + col;
  float bv = bias ? bias[n] : 0.0f;
#pragma unroll
  for (int r = 0; r < 4; ++r) {
    int m = bm + mi * 16 + quad * 4 + r;
    float val = acc[r] + bv;
    if (relu) val = fmaxf(val, 0.0f);
    Cp[(long)m * Cm + (long)n * Cn] = val;
  }
}

// ---------------- causal attention, one (b,h) per block -------------------
__global__ __launch_bounds__(256) void attn_k(const float* __restrict__ qkv,
                                              float* __restrict__ ctx) {
  __shared__ float q[T_][HD_ + 1];
  __shared__ float k[T_][HD_ + 1];
  __shared__ float v[T_][HD_ + 1];
  __shared__ float s[T_][T_ + 1];
  int h = blockIdx.x, b = blockIdx.y;
  int tid = threadIdx.x;
  for (int idx = tid; idx < T_ * HD_; idx += 256) {
    int t = idx >> 6, d = idx & 63;
    long base = (long)(b * T_ + t) * (3 * D_) + h * HD_ + d;
    q[t][d] = qkv[base];
    k[t][d] = qkv[base + D_];
    v[t][d] = qkv[base + 2 * D_];
  }
  __syncthreads();
  for (int idx = tid; idx < T_ * T_; idx += 256) {
    int i = idx / T_, j = idx - i * T_;
    if (j <= i) {
      float acc = 0.f;
#pragma unroll
      for (int d = 0; d < HD_; ++d) acc += q[i][d] * k[j][d];
      s[i][j] = acc * 0.125f;  // 1/sqrt(64)
    }
  }
  __syncthreads();
  if (tid < T_) {
    int i = tid;
    float mx = -1e30f;
    for (int j = 0; j <= i; ++j) mx = fmaxf(mx, s[i][j]);
    float sum = 0.f;
    for (int j = 0; j <= i; ++j) {
      float e = __expf(s[i][j] - mx);
      s[i][j] = e;
      sum += e;
    }
    float inv = 1.0f / sum;
    for (int j = 0; j <= i; ++j) s[i][j] *= inv;
  }
  __syncthreads();
  for (int idx = tid; idx < T_ * HD_; idx += 256) {
    int i = idx >> 6, d = idx & 63;
    float acc = 0.f;
    for (int j = 0; j <= i; ++j) acc += s[i][j] * v[j][d];
    ctx[(long)(b * T_ + i) * D_ + h * HD_ + d] = acc;
  }
}

// ---------------- residual + LayerNorm, one (b,t) per block ---------------
__global__ __launch_bounds__(256) void ln_k(float* __restrict__ x, const float* __restrict__ y,
                                            const float* __restrict__ g,
                                            const float* __restrict__ be) {
  __shared__ float red[4];
  int m = blockIdx.x, d = threadIdx.x;
  int lane = d & 63, wv = d >> 6;
  float val = x[m * D_ + d] + y[m * D_ + d];
  float sv = val;
#pragma unroll
  for (int mk = 1; mk < 64; mk <<= 1) sv += __shfl_xor(sv, mk);
  if (lane == 0) red[wv] = sv;
  __syncthreads();
  float mean = (red[0] + red[1] + red[2] + red[3]) * (1.0f / D_);
  __syncthreads();
  float c = val - mean;
  float s2 = c * c;
#pragma unroll
  for (int mk = 1; mk < 64; mk <<= 1) s2 += __shfl_xor(s2, mk);
  if (lane == 0) red[wv] = s2;
  __syncthreads();
  float var = (red[0] + red[1] + red[2] + red[3]) * (1.0f / D_);
  x[m * D_ + d] = c * rsqrtf(var + EPS_) * g[d] + be[d];
}

// ---------------- final: out[b,p,t] = sigmoid(sum_e gelu(pp+cp)*we + beff) -
// grid (P/64, T/4, B); each wave owns one t, lanes own p.
// gelu via exp2+rcp:  u = -w*log2e = x * (-2.3022083 - 0.1029432 x^2)
__global__ __launch_bounds__(256) void final_k(const float* __restrict__ pprojT,
                                               const float* __restrict__ cw,
                                               const int* __restrict__ tokens,
                                               const float* __restrict__ cls_w,
                                               const float* __restrict__ cls_b,
                                               const float* __restrict__ fus_b2,
                                               float* __restrict__ out) {
  int lane = threadIdx.x & 63, wv = threadIdx.x >> 6;
  int p = blockIdx.x * 64 + lane;
  int t = blockIdx.y * 4 + wv;
  int b = blockIdx.z;
  int m = b * T_ + t;
  // beff[m] = dot(cls_w[tok], fus_b2) + cls_b[tok], wave-reduced
  int tok = tokens[m];
  const float* cr = cls_w + (long)tok * D_;
  float bacc = 0.f;
#pragma unroll
  for (int i = 0; i < 4; ++i) bacc += cr[lane + i * 64] * fus_b2[lane + i * 64];
#pragma unroll
  for (int mk = 1; mk < 64; mk <<= 1) bacc += __shfl_xor(bacc, mk);
  float beff = bacc + cls_b[tok];

  const float* ppb = pprojT + (long)b * (D_ * P_);        // [e][p]
  const float* cwt = cw + (long)m * (D_ * 2);             // {cproj, weff} pairs
  float acc = 0.f;
#pragma unroll 8
  for (int e = 0; e < D_; ++e) {
    float pp = ppb[e * P_ + p];
    float2 c = *(const float2*)&cwt[e * 2];
    float x = pp + c.x;
    float x2 = x * x;
    float u = x * fmaf(-0.1029432f, x2, -2.3022083f);
    float ex = __builtin_amdgcn_exp2f(u);
    float r = __builtin_amdgcn_rcpf(1.0f + ex);
    acc = fmaf(x * r, c.y, acc);
  }
  float logit = acc + beff;
  float es = __builtin_amdgcn_exp2f(-1.4426950408889634f * logit);
  out[(long)(b * P_ + p) * T_ + t] = __builtin_amdgcn_rcpf(1.0f + es);
}

extern "C" void kernel_launch(void* const* d_in, const int* in_sizes, int n_in, void* d_out,
                              int out_size, void* d_ws, size_t ws_size, hipStream_t stream) {
  const float* patches = (const float*)d_in[0];
  const int* tokens = (const int*)d_in[1];
  const float* tok_emb = (const float*)d_in[2];
  const float* pos_emb = (const float*)d_in[3];
  const float* qkv_w = (const float*)d_in[4];
  const float* qkv_b = (const float*)d_in[5];
  const float* out_w = (const float*)d_in[6];
  const float* out_b = (const float*)d_in[7];
  const float* ln1_s = (const float*)d_in[8];
  const float* ln1_b = (const float*)d_in[9];
  const float* w1 = (const float*)d_in[10];
  const float* b1 = (const float*)d_in[11];
  const float* w2 = (const float*)d_in[12];
  const float* b2 = (const float*)d_in[13];
  const float* ln2_s = (const float*)d_in[14];
  const float* ln2_b = (const float*)d_in[15];
  const float* fus_w1 = (const float*)d_in[16];
  const float* fus_b1 = (const float*)d_in[17];
  const float* fus_w2 = (const float*)d_in[18];
  const float* fus_b2 = (const float*)d_in[19];
  const float* cls_w = (const float*)d_in[20];
  const float* cls_b = (const float*)d_in[21];
  float* out = (float*)d_out;

  float* xbuf = (float*)d_ws;                    // 1280*256
  float* qkvbuf = xbuf + B_ * T_ * D_;           // 1280*768
  float* tmp = qkvbuf + B_ * T_ * 3 * D_;        // 1280*256
  float* hbuf = tmp + B_ * T_ * D_;              // 1280*1024
  float* pprojT = hbuf + B_ * T_ * DFF_;         // 32*256*256 [b][e][p]
  float* cwbuf = pprojT + (long)B_ * D_ * P_;    // 1280*256*2 interleaved {cproj,weff}
  float* w2T = cwbuf + B_ * T_ * D_ * 2;         // 256*256 (fus_w2 transposed)

  const int MT = B_ * T_;  // 1280

  prep_k<<<MT + 64, 256, 0, stream>>>(tokens, tok_emb, pos_emb, xbuf, fus_w2, w2T);

  for (int l = 0; l < L_; ++l) {
    // qkv = x @ qkv_w^T + qkv_b
    gemmd_k<<<dim3(24, 40, 1), 256, 0, stream>>>(
        xbuf, qkv_w + (long)l * 3 * D_ * D_, qkv_b + l * 3 * D_, qkvbuf, D_, D_, D_,
        3 * D_, 1, 0, 0, 0, 0, nullptr);
    attn_k<<<dim3(H_, B_), 256, 0, stream>>>(qkvbuf, hbuf);
    // proj = ctx @ out_w^T + out_b
    gemmd_k<<<dim3(8, 40, 1), 256, 0, stream>>>(
        hbuf, out_w + (long)l * D_ * D_, out_b + l * D_, tmp, D_, D_, D_, D_, 1,
        0, 0, 0, 0, nullptr);
    ln_k<<<MT, D_, 0, stream>>>(xbuf, tmp, ln1_s + l * D_, ln1_b + l * D_);
    // h = relu(x @ w1^T + b1)
    gemmd_k<<<dim3(32, 40, 1), 256, 0, stream>>>(
        xbuf, w1 + (long)l * DFF_ * D_, b1 + l * DFF_, hbuf, D_, D_, D_, DFF_, 1,
        0, 0, 1, 0, nullptr);
    // y = h @ w2^T + b2
    gemmd_k<<<dim3(8, 40, 1), 256, 0, stream>>>(
        hbuf, w2 + (long)l * D_ * DFF_, b2 + l * D_, tmp, DFF_, DFF_, DFF_, D_, 1,
        0, 0, 0, 0, nullptr);
    ln_k<<<MT, D_, 0, stream>>>(xbuf, tmp, ln2_s + l * D_, ln2_b + l * D_);
  }

  // pproj[b][e][p] = (patches @ wp^T)^T  (batched over b, transposed out)
  gemmd_k<<<dim3(8, 8, B_), 256, 0, stream>>>(
      patches, fus_w1, nullptr, pprojT, DINO_, DINO_, DINO_ + D_, 1, P_,
      (long)P_ * DINO_, (long)D_ * P_, 0, 0, nullptr);
  // cproj (even slots of cw), ctx-shift fused: row t==0 -> zeros, else x[m-1]
  gemmd_k<<<dim3(8, 40, 1), 256, 0, stream>>>(
      xbuf, fus_w1 + DINO_, fus_b1, cwbuf, D_, D_, DINO_ + D_, 2 * D_, 2,
      0, 0, 0, 1, nullptr);
  // weff = cls_w[tokens] @ fus_w2 (odd slots of cw), gather fused, via w2T
  gemmd_k<<<dim3(8, 40, 1), 256, 0, stream>>>(
      cls_w, w2T, nullptr, cwbuf + 1, D_, D_, D_, 2 * D_, 2,
      0, 0, 0, 0, tokens);

  final_k<<<dim3(4, 10, 32), 256, 0, stream>>>(pprojT, cwbuf, tokens, cls_w, cls_b,
                                               fus_b2, out);
}

// Round 6
// 269.845 us; speedup vs baseline: 1.5314x; 1.5314x over previous
//
#include <hip/hip_runtime.h>
#include <hip/hip_bf16.h>

#define B_ 32
#define T_ 40
#define P_ 256
#define V_ 4096
#define D_ 256
#define DINO_ 384
#define H_ 4
#define L_ 2
#define HD_ 64
#define DFF_ 1024
#define EPS_ 1e-5f

typedef __bf16 bf16;
typedef __bf16 bf16x8 __attribute__((ext_vector_type(8)));
typedef float f32x4 __attribute__((ext_vector_type(4)));

// bf16 weight arena offsets (elements)
#define OFF_QKV 0            // 2 x 768*256
#define OFF_OUTW 393216      // 2 x 256*256
#define OFF_W1 524288        // 2 x 1024*256
#define OFF_W2 1048576       // 2 x 256*1024
#define OFF_FUS 1572864      // 256*640
#define WB_TOTAL 1736704
#define CONV_BLOCKS 848      // WB_TOTAL / 2048

__device__ __forceinline__ bf16x8 cvt8(const float* p) {
  float4 f0 = *(const float4*)p;
  float4 f1 = *(const float4*)(p + 4);
  bf16x8 v;
  v[0] = (bf16)f0.x; v[1] = (bf16)f0.y; v[2] = (bf16)f0.z; v[3] = (bf16)f0.w;
  v[4] = (bf16)f1.x; v[5] = (bf16)f1.y; v[6] = (bf16)f1.z; v[7] = (bf16)f1.w;
  return v;
}

// ---- prep: embed (blocks<1280) | fus_w2 transpose->bf16 (64) | weights->bf16
__global__ __launch_bounds__(256) void prep_k(
    const int* __restrict__ tokens, const float* __restrict__ tok_emb,
    const float* __restrict__ pos_emb, float* __restrict__ x,
    const float* __restrict__ fus_w2, bf16* __restrict__ w2Tb,
    const float* __restrict__ qkv_w, const float* __restrict__ out_w,
    const float* __restrict__ w1, const float* __restrict__ w2,
    const float* __restrict__ fus_w1, bf16* __restrict__ wb) {
  __shared__ float tile[32][33];
  int bi = blockIdx.x;
  int tid = threadIdx.x;
  if (bi < B_ * T_) {
    int t = bi % T_;
    x[bi * D_ + tid] = tok_emb[tokens[bi] * D_ + tid] + pos_emb[t * D_ + tid];
  } else if (bi < B_ * T_ + 64) {
    int tt = bi - B_ * T_;
    int bx = (tt & 7) * 32, by = (tt >> 3) * 32;
    int tx = tid & 31, ty = tid >> 5;  // 32 x 8
#pragma unroll
    for (int i = 0; i < 32; i += 8) tile[ty + i][tx] = fus_w2[(by + ty + i) * D_ + bx + tx];
    __syncthreads();
#pragma unroll
    for (int i = 0; i < 32; i += 8)
      w2Tb[(bx + ty + i) * D_ + by + tx] = (bf16)tile[tx][ty + i];
  } else {
    long f = (long)(bi - B_ * T_ - 64) * 2048 + tid * 8;  // whole block same range
    const float* src;
    long off;
    if (f < OFF_OUTW)      { src = qkv_w;  off = f - OFF_QKV; }
    else if (f < OFF_W1)   { src = out_w;  off = f - OFF_OUTW; }
    else if (f < OFF_W2)   { src = w1;     off = f - OFF_W1; }
    else if (f < OFF_FUS)  { src = w2;     off = f - OFF_W2; }
    else                   { src = fus_w1; off = f - OFF_FUS; }
    *(bf16x8*)&wb[f] = cvt8(src + off);
  }
}

// ---- staged MFMA GEMM: 32x32 tile, 4 waves; C[m,n]=act(A@W^T+bias), W bf16
__global__ __launch_bounds__(256) void gemm_k(
    const float* __restrict__ A, const bf16* __restrict__ W,
    const float* __restrict__ bias, float* __restrict__ out,
    int K, int lda, int ldw, int ldc, int relu) {
  __shared__ bf16 As[32 * 72];
  __shared__ bf16 Ws[32 * 72];
  const int tid = threadIdx.x;
  const int lane = tid & 63;
  const int wv = tid >> 6;
  const int mi = wv & 1, ni = wv >> 1;
  const int col = lane & 15;
  const int quad = lane >> 4;
  const int bn = blockIdx.x * 32;
  const int bm = blockIdx.y * 32;
  const int srow = tid >> 3;      // 0..31
  const int kc = (tid & 7) * 8;   // 0..56
  const float* Ap = A + (long)(bm + srow) * lda;
  const bf16* Wp = W + (long)(bn + srow) * ldw;

  f32x4 acc = {0.f, 0.f, 0.f, 0.f};
  for (int kk = 0; kk < K; kk += 64) {
    *(bf16x8*)&As[srow * 72 + kc] = cvt8(Ap + kk + kc);
    *(bf16x8*)&Ws[srow * 72 + kc] = *(const bf16x8*)(Wp + kk + kc);
    __syncthreads();
#pragma unroll
    for (int ki = 0; ki < 2; ++ki) {
      bf16x8 afr = *(const bf16x8*)&As[(mi * 16 + col) * 72 + ki * 32 + quad * 8];
      bf16x8 bfr = *(const bf16x8*)&Ws[(ni * 16 + col) * 72 + ki * 32 + quad * 8];
      acc = __builtin_amdgcn_mfma_f32_16x16x32_bf16(afr, bfr, acc, 0, 0, 0);
    }
    __syncthreads();
  }
  const int n = bn + ni * 16 + col;
  float bv = bias ? bias[n] : 0.0f;
#pragma unroll
  for (int r = 0; r < 4; ++r) {
    int m = bm + mi * 16 + quad * 4 + r;
    float val = acc[r] + bv;
    if (relu) val = fmaxf(val, 0.0f);
    out[(long)m * ldc + n] = val;
  }
}

// ---- fused pproj/cproj/weff (one launch, grid y-ranges), 32x32 staged -----
// y<256: pproj  C->pprojT[b][e][p];  y<296: cproj (ctx-shift) -> cw even;
// else: weff (token-gathered cls_w rows @ w2T) -> cw odd.
__global__ __launch_bounds__(256) void fuse3_k(
    const float* __restrict__ patches, const float* __restrict__ xbuf,
    const float* __restrict__ cls_w, const bf16* __restrict__ fusb,
    const bf16* __restrict__ w2Tb, const float* __restrict__ fus_b1,
    const int* __restrict__ tokens, float* __restrict__ pprojT,
    float* __restrict__ cw) {
  __shared__ bf16 As[32 * 72];
  __shared__ bf16 Ws[32 * 72];
  const int tid = threadIdx.x;
  const int lane = tid & 63;
  const int wv = tid >> 6;
  const int mi = wv & 1, ni = wv >> 1;
  const int col = lane & 15;
  const int quad = lane >> 4;
  const int bn = blockIdx.x * 32;
  const int y = blockIdx.y;
  const int srow = tid >> 3;
  const int kc = (tid & 7) * 8;

  int job, bm;
  if (y < 256) { job = 0; bm = y * 32; }
  else if (y < 296) { job = 1; bm = (y - 256) * 32; }
  else { job = 2; bm = (y - 296) * 32; }
  const int gm = bm + srow;

  const float* Ap;
  const bf16* Wp;
  int K;
  bool zeroA = false;
  if (job == 0) {
    Ap = patches + (long)gm * DINO_;
    Wp = fusb + (long)(bn + srow) * 640;
    K = DINO_;
  } else if (job == 1) {
    int t = gm % T_;
    zeroA = (t == 0);
    Ap = xbuf + (long)(zeroA ? gm : gm - 1) * D_;
    Wp = fusb + 384 + (long)(bn + srow) * 640;
    K = D_;
  } else {
    Ap = cls_w + (long)tokens[gm] * D_;
    Wp = w2Tb + (long)(bn + srow) * D_;
    K = D_;
  }

  f32x4 acc = {0.f, 0.f, 0.f, 0.f};
  bf16x8 z8 = {};
  for (int kk = 0; kk < K; kk += 64) {
    bf16x8 av = zeroA ? z8 : cvt8(Ap + kk + kc);
    *(bf16x8*)&As[srow * 72 + kc] = av;
    *(bf16x8*)&Ws[srow * 72 + kc] = *(const bf16x8*)(Wp + kk + kc);
    __syncthreads();
#pragma unroll
    for (int ki = 0; ki < 2; ++ki) {
      bf16x8 afr = *(const bf16x8*)&As[(mi * 16 + col) * 72 + ki * 32 + quad * 8];
      bf16x8 bfr = *(const bf16x8*)&Ws[(ni * 16 + col) * 72 + ki * 32 + quad * 8];
      acc = __builtin_amdgcn_mfma_f32_16x16x32_bf16(afr, bfr, acc, 0, 0, 0);
    }
    __syncthreads();
  }
  const int n = bn + ni * 16 + col;
  if (job == 0) {
#pragma unroll
    for (int r = 0; r < 4; ++r) {
      int m = bm + mi * 16 + quad * 4 + r;
      int b = m >> 8, p = m & 255;
      pprojT[(long)b * (D_ * P_) + (long)n * P_ + p] = acc[r];
    }
  } else if (job == 1) {
    float bv = fus_b1[n];
#pragma unroll
    for (int r = 0; r < 4; ++r) {
      int m = bm + mi * 16 + quad * 4 + r;
      cw[(long)m * (2 * D_) + n * 2] = acc[r] + bv;
    }
  } else {
#pragma unroll
    for (int r = 0; r < 4; ++r) {
      int m = bm + mi * 16 + quad * 4 + r;
      cw[(long)m * (2 * D_) + n * 2 + 1] = acc[r];
    }
  }
}

// ---- causal attention, one (b,h) per block --------------------------------
__global__ __launch_bounds__(256) void attn_k(const float* __restrict__ qkv,
                                              float* __restrict__ ctx) {
  __shared__ float q[T_][HD_ + 1];
  __shared__ float k[T_][HD_ + 1];
  __shared__ float v[T_][HD_ + 1];
  __shared__ float s[T_][T_ + 1];
  int h = blockIdx.x, b = blockIdx.y;
  int tid = threadIdx.x;
  for (int idx = tid; idx < T_ * HD_; idx += 256) {
    int t = idx >> 6, d = idx & 63;
    long base = (long)(b * T_ + t) * (3 * D_) + h * HD_ + d;
    q[t][d] = qkv[base];
    k[t][d] = qkv[base + D_];
    v[t][d] = qkv[base + 2 * D_];
  }
  __syncthreads();
  for (int idx = tid; idx < T_ * T_; idx += 256) {
    int i = idx / T_, j = idx - i * T_;
    if (j <= i) {
      float acc = 0.f;
#pragma unroll
      for (int d = 0; d < HD_; ++d) acc += q[i][d] * k[j][d];
      s[i][j] = acc * 0.125f;
    }
  }
  __syncthreads();
  if (tid < T_) {
    int i = tid;
    float mx = -1e30f;
    for (int j = 0; j <= i; ++j) mx = fmaxf(mx, s[i][j]);
    float sum = 0.f;
    for (int j = 0; j <= i; ++j) {
      float e = __expf(s[i][j] - mx);
      s[i][j] = e;
      sum += e;
    }
    float inv = 1.0f / sum;
    for (int j = 0; j <= i; ++j) s[i][j] *= inv;
  }
  __syncthreads();
  for (int idx = tid; idx < T_ * HD_; idx += 256) {
    int i = idx >> 6, d = idx & 63;
    float acc = 0.f;
    for (int j = 0; j <= i; ++j) acc += s[i][j] * v[j][d];
    ctx[(long)(b * T_ + i) * D_ + h * HD_ + d] = acc;
  }
}

// ---- residual + LayerNorm -------------------------------------------------
__global__ __launch_bounds__(256) void ln_k(float* __restrict__ x, const float* __restrict__ y,
                                            const float* __restrict__ g,
                                            const float* __restrict__ be) {
  __shared__ float red[4];
  int m = blockIdx.x, d = threadIdx.x;
  int lane = d & 63, wv = d >> 6;
  float val = x[m * D_ + d] + y[m * D_ + d];
  float sv = val;
#pragma unroll
  for (int mk = 1; mk < 64; mk <<= 1) sv += __shfl_xor(sv, mk);
  if (lane == 0) red[wv] = sv;
  __syncthreads();
  float mean = (red[0] + red[1] + red[2] + red[3]) * (1.0f / D_);
  __syncthreads();
  float c = val - mean;
  float s2 = c * c;
#pragma unroll
  for (int mk = 1; mk < 64; mk <<= 1) s2 += __shfl_xor(s2, mk);
  if (lane == 0) red[wv] = s2;
  __syncthreads();
  float var = (red[0] + red[1] + red[2] + red[3]) * (1.0f / D_);
  x[m * D_ + d] = c * rsqrtf(var + EPS_) * g[d] + be[d];
}

// ---- final: out[b,p,t] = sigmoid(sum_e gelu(pp+cp)*we + beff) -------------
__global__ __launch_bounds__(256) void final_k(const float* __restrict__ pprojT,
                                               const float* __restrict__ cw,
                                               const int* __restrict__ tokens,
                                               const float* __restrict__ cls_w,
                                               const float* __restrict__ cls_b,
                                               const float* __restrict__ fus_b2,
                                               float* __restrict__ out) {
  int lane = threadIdx.x & 63, wv = threadIdx.x >> 6;
  int p = blockIdx.x * 64 + lane;
  int t = blockIdx.y * 4 + wv;
  int b = blockIdx.z;
  int m = b * T_ + t;
  int tok = tokens[m];
  const float* cr = cls_w + (long)tok * D_;
  float bacc = 0.f;
#pragma unroll
  for (int i = 0; i < 4; ++i) bacc += cr[lane + i * 64] * fus_b2[lane + i * 64];
#pragma unroll
  for (int mk = 1; mk < 64; mk <<= 1) bacc += __shfl_xor(bacc, mk);
  float beff = bacc + cls_b[tok];

  const float* ppb = pprojT + (long)b * (D_ * P_);  // [e][p]
  const float* cwt = cw + (long)m * (D_ * 2);       // {cproj, weff}
  float acc = 0.f;
#pragma unroll 8
  for (int e = 0; e < D_; ++e) {
    float pp = ppb[e * P_ + p];
    float2 c = *(const float2*)&cwt[e * 2];
    float x = pp + c.x;
    float x2 = x * x;
    float u = x * fmaf(-0.1029432f, x2, -2.3022083f);   // -log2e*1.5958*(x+0.044715x^3)
    float ex = __builtin_amdgcn_exp2f(u);
    float r = __builtin_amdgcn_rcpf(1.0f + ex);
    acc = fmaf(x * r, c.y, acc);
  }
  float logit = acc + beff;
  float es = __builtin_amdgcn_exp2f(-1.4426950408889634f * logit);
  out[(long)(b * P_ + p) * T_ + t] = __builtin_amdgcn_rcpf(1.0f + es);
}

extern "C" void kernel_launch(void* const* d_in, const int* in_sizes, int n_in, void* d_out,
                              int out_size, void* d_ws, size_t ws_size, hipStream_t stream) {
  const float* patches = (const float*)d_in[0];
  const int* tokens = (const int*)d_in[1];
  const float* tok_emb = (const float*)d_in[2];
  const float* pos_emb = (const float*)d_in[3];
  const float* qkv_w = (const float*)d_in[4];
  const float* qkv_b = (const float*)d_in[5];
  const float* out_w = (const float*)d_in[6];
  const float* out_b = (const float*)d_in[7];
  const float* ln1_s = (const float*)d_in[8];
  const float* ln1_b = (const float*)d_in[9];
  const float* w1 = (const float*)d_in[10];
  const float* b1 = (const float*)d_in[11];
  const float* w2 = (const float*)d_in[12];
  const float* b2 = (const float*)d_in[13];
  const float* ln2_s = (const float*)d_in[14];
  const float* ln2_b = (const float*)d_in[15];
  const float* fus_w1 = (const float*)d_in[16];
  const float* fus_b1 = (const float*)d_in[17];
  const float* fus_w2 = (const float*)d_in[18];
  const float* fus_b2 = (const float*)d_in[19];
  const float* cls_w = (const float*)d_in[20];
  const float* cls_b = (const float*)d_in[21];
  float* out = (float*)d_out;

  float* xbuf = (float*)d_ws;                    // 1280*256
  float* qkvbuf = xbuf + B_ * T_ * D_;           // 1280*768
  float* tmp = qkvbuf + B_ * T_ * 3 * D_;        // 1280*256
  float* hbuf = tmp + B_ * T_ * D_;              // 1280*1024
  float* pprojT = hbuf + B_ * T_ * DFF_;         // 32*256*256 [b][e][p]
  float* cwbuf = pprojT + (long)B_ * D_ * P_;    // 1280*256*2 {cproj,weff}
  bf16* wb = (bf16*)(cwbuf + B_ * T_ * D_ * 2);  // bf16 weight arena
  bf16* w2Tb = wb + WB_TOTAL;                    // 256*256

  const int MT = B_ * T_;  // 1280

  prep_k<<<MT + 64 + CONV_BLOCKS, 256, 0, stream>>>(
      tokens, tok_emb, pos_emb, xbuf, fus_w2, w2Tb, qkv_w, out_w, w1, w2, fus_w1, wb);

  for (int l = 0; l < L_; ++l) {
    gemm_k<<<dim3(24, 40), 256, 0, stream>>>(
        xbuf, wb + OFF_QKV + (long)l * 3 * D_ * D_, qkv_b + l * 3 * D_, qkvbuf,
        D_, D_, D_, 3 * D_, 0);
    attn_k<<<dim3(H_, B_), 256, 0, stream>>>(qkvbuf, hbuf);
    gemm_k<<<dim3(8, 40), 256, 0, stream>>>(
        hbuf, wb + OFF_OUTW + (long)l * D_ * D_, out_b + l * D_, tmp,
        D_, D_, D_, D_, 0);
    ln_k<<<MT, D_, 0, stream>>>(xbuf, tmp, ln1_s + l * D_, ln1_b + l * D_);
    gemm_k<<<dim3(32, 40), 256, 0, stream>>>(
        xbuf, wb + OFF_W1 + (long)l * DFF_ * D_, b1 + l * DFF_, hbuf,
        D_, D_, D_, DFF_, 1);
    gemm_k<<<dim3(8, 40), 256, 0, stream>>>(
        hbuf, wb + OFF_W2 + (long)l * D_ * DFF_, b2 + l * D_, tmp,
        DFF_, DFF_, DFF_, D_, 0);
    ln_k<<<MT, D_, 0, stream>>>(xbuf, tmp, ln2_s + l * D_, ln2_b + l * D_);
  }

  fuse3_k<<<dim3(8, 336), 256, 0, stream>>>(patches, xbuf, cls_w, wb + OFF_FUS, w2Tb,
                                            fus_b1, tokens, pprojT, cwbuf);

  final_k<<<dim3(4, 10, 32), 256, 0, stream>>>(pprojT, cwbuf, tokens, cls_w, cls_b,
                                               fus_b2, out);
}